// Round 3
// baseline (1056.032 us; speedup 1.0000x reference)
//
#include <hip/hip_runtime.h>
#include <hip/hip_bf16.h>

#define BB 4
#define SS 2048
#define DD 512
#define HH 8
#define HDIM 64

typedef __attribute__((ext_vector_type(8))) short bf16x8;
typedef __attribute__((ext_vector_type(4))) float floatx4;
typedef __attribute__((ext_vector_type(8))) unsigned short u16x8;

static __device__ __forceinline__ unsigned short f2bf(float x) {
  __hip_bfloat16 h = __float2bfloat16(x);
  unsigned short u;
  __builtin_memcpy(&u, &h, sizeof(u));
  return u;
}
static __device__ __forceinline__ float bf2f(unsigned short u) {
  union { unsigned int i; float f; } c;
  c.i = ((unsigned int)u) << 16;
  return c.f;
}
static __device__ __forceinline__ void split1(float x, unsigned short& h, unsigned short& l) {
  h = f2bf(x);
  l = f2bf(x - bf2f(h));     // exact residual, second bf16 term
}
static __device__ __forceinline__ void gload_lds16(const void* g, void* l) {
  __builtin_amdgcn_global_load_lds((const __attribute__((address_space(1))) void*)g,
                                   (__attribute__((address_space(3))) void*)l, 16, 0, 0);
}

// LDS XOR swizzle for 128B-stride rows (granularity: 8 ushorts = 16B)
#define SWZ(row, col) ((col) ^ (((row) & 7) * 8))

// ---------------- activation hi/lo split: fp32 [8192,512] -> two bf16 planes ----------------
__global__ __launch_bounds__(256)
void asplit_kernel(const float* __restrict__ src, unsigned short* __restrict__ H,
                   unsigned short* __restrict__ L)
{
  const size_t i = ((size_t)blockIdx.x * 256 + threadIdx.x) * 8;
  float4 f0 = *(const float4*)&src[i];
  float4 f1 = *(const float4*)&src[i + 4];
  float ff[8] = {f0.x, f0.y, f0.z, f0.w, f1.x, f1.y, f1.z, f1.w};
  u16x8 hv, lv;
#pragma unroll
  for (int j = 0; j < 8; ++j) {
    unsigned short h, l;
    split1(ff[j], h, l);
    hv[j] = h; lv[j] = l;
  }
  *(u16x8*)&H[i] = hv;
  *(u16x8*)&L[i] = lv;
}

// ---------------- weight transpose + hi/lo bf16 split ----------------
__global__ __launch_bounds__(256)
void wsplit_kernel(const float* __restrict__ Wq, const float* __restrict__ Wk,
                   const float* __restrict__ Wv, const float* __restrict__ Wo,
                   const float* __restrict__ Wg, const float* __restrict__ Wmq,
                   const float* __restrict__ Wmk, unsigned short* __restrict__ wsb)
{
  const int bx = blockIdx.x;
  const float* src; unsigned short* dh; unsigned short* dl; int K, N, tile;
  if (bx < 64)       { src = Wq;  dh = wsb + 0;       dl = wsb + 262144;  K = 512; N = 512; tile = bx; }
  else if (bx < 128) { src = Wk;  dh = wsb + 524288;  dl = wsb + 786432;  K = 512; N = 512; tile = bx - 64; }
  else if (bx < 192) { src = Wv;  dh = wsb + 1048576; dl = wsb + 1310720; K = 512; N = 512; tile = bx - 128; }
  else if (bx < 256) { src = Wo;  dh = wsb + 1572864; dl = wsb + 1835008; K = 512; N = 512; tile = bx - 192; }
  else if (bx < 272) { src = Wg;  dh = wsb + 2097152; dl = wsb + 2162688; K = 512; N = 128; tile = bx - 256; }
  else if (bx < 288) { src = Wmq; dh = wsb + 2228224; dl = wsb + 2293760; K = 128; N = 512; tile = bx - 272; }
  else               { src = Wmk; dh = wsb + 2359296; dl = wsb + 2424832; K = 128; N = 512; tile = bx - 288; }
  const int nt = N >> 6;
  const int k0 = (tile / nt) * 64, n0 = (tile % nt) * 64;
  __shared__ float T[64][65];
  const int t = threadIdx.x;
  const int r = t >> 2, c = (t & 3) * 16;
#pragma unroll
  for (int j = 0; j < 16; j += 4)
    *(float4*)&T[r][c + j] = *(const float4*)&src[(size_t)(k0 + r) * N + n0 + c + j];
  __syncthreads();
  u16x8 hv[2], lv[2];
#pragma unroll
  for (int j = 0; j < 16; ++j) {
    unsigned short h, l;
    split1(T[c + j][r], h, l);
    hv[j >> 3][j & 7] = h;
    lv[j >> 3][j & 7] = l;
  }
  const size_t di = (size_t)(n0 + r) * K + k0 + c;
  *(u16x8*)&dh[di]     = hv[0];
  *(u16x8*)&dh[di + 8] = hv[1];
  *(u16x8*)&dl[di]     = lv[0];
  *(u16x8*)&dl[di + 8] = lv[1];
}

// ---------------- 3-term split-bf16 MFMA GEMM, full global_load_lds staging ----------------
// A planes [M][K] bf16 (hi/lo), W planes [N][K] bf16 (hi/lo). BK=32.
// EPI: 0 fp32 | 2 bf16 | 4 bf16*(mod16*sc) | 6 relu->split planes | 7 sigmoid bf16
template<int BM, int BN, int EPI, bool SG>
__global__ __launch_bounds__(256)
void mgemm_kernel(const unsigned short* __restrict__ AH, const unsigned short* __restrict__ AL,
                  const unsigned short* __restrict__ WH, const unsigned short* __restrict__ WL,
                  const float* __restrict__ bias, const unsigned short* __restrict__ mod16,
                  const float sc, float* __restrict__ Cf, unsigned short* __restrict__ C16,
                  unsigned short* __restrict__ CH, unsigned short* __restrict__ CL,
                  int K, int N)
{
  constexpr int HM = BM / 2, HN = BN / 2, FM = BM / 32, FN = BN / 32;
  constexpr int AU = BM * 4;            // 16B units per A plane per k-step
  constexpr int AIT = (2 * AU) / 256;
  constexpr int BU = BN * 4;
  constexpr int BIT = (2 * BU) / 256;
  __shared__ alignas(16) unsigned short AhS[BM][32], AlS[BM][32], BhS[BN][32], BlS[BN][32];
  const int t = threadIdx.x;
  const int wid = t >> 6, lane = t & 63, quad = lane >> 4, l16 = lane & 15;
  const int wm = wid >> 1, wn = wid & 1;
  int m0, n0;
  if constexpr (SG) {   // m-grouped XCD swizzle: all n-tiles of an m-panel share an XCD
    const int d = blockIdx.x;
    m0 = (((d & 7) << 3) | ((d >> 3) & 7)) * BM;
    n0 = (d >> 6) * BN;
  } else {
    m0 = blockIdx.y * BM;
    n0 = blockIdx.x * BN;
  }

  floatx4 acc[FM][FN];
#pragma unroll
  for (int i = 0; i < FM; ++i)
#pragma unroll
    for (int j = 0; j < FN; ++j) {
      floatx4 z = {0.f, 0.f, 0.f, 0.f};
      acc[i][j] = z;
    }

  for (int k0 = 0; k0 < K; k0 += 32) {
    __syncthreads();
#pragma unroll
    for (int it = 0; it < AIT; ++it) {
      const int uid = it * 256 + t;
      const int pl = uid >= AU;              // wave-uniform per it
      const int u = uid & (AU - 1);
      const int row = u >> 2, cu = (u & 3) ^ (row & 3);
      gload_lds16((pl ? AL : AH) + (size_t)(m0 + row) * K + k0 + cu * 8,
                  (pl ? &AlS[0][0] : &AhS[0][0]) + u * 8);
    }
#pragma unroll
    for (int it = 0; it < BIT; ++it) {
      const int uid = it * 256 + t;
      const int pl = uid >= BU;
      const int u = uid & (BU - 1);
      const int row = u >> 2, cu = (u & 3) ^ (row & 3);
      gload_lds16((pl ? WL : WH) + (size_t)(n0 + row) * K + k0 + cu * 8,
                  (pl ? &BlS[0][0] : &BhS[0][0]) + u * 8);
    }
    __syncthreads();
    const int swf = (l16 & 3) * 8;
    bf16x8 fah[FM], fal[FM], fbh[FN], fbl[FN];
#pragma unroll
    for (int mi = 0; mi < FM; ++mi) {
      const int rr = wm * HM + mi * 16 + l16;
      fah[mi] = *(const bf16x8*)&AhS[rr][(quad * 8) ^ swf];
      fal[mi] = *(const bf16x8*)&AlS[rr][(quad * 8) ^ swf];
    }
#pragma unroll
    for (int ni = 0; ni < FN; ++ni) {
      const int rr = wn * HN + ni * 16 + l16;
      fbh[ni] = *(const bf16x8*)&BhS[rr][(quad * 8) ^ swf];
      fbl[ni] = *(const bf16x8*)&BlS[rr][(quad * 8) ^ swf];
    }
#pragma unroll
    for (int mi = 0; mi < FM; ++mi)
#pragma unroll
      for (int ni = 0; ni < FN; ++ni) {
        acc[mi][ni] = __builtin_amdgcn_mfma_f32_16x16x32_bf16(fah[mi], fbh[ni], acc[mi][ni], 0, 0, 0);
        acc[mi][ni] = __builtin_amdgcn_mfma_f32_16x16x32_bf16(fal[mi], fbh[ni], acc[mi][ni], 0, 0, 0);
        acc[mi][ni] = __builtin_amdgcn_mfma_f32_16x16x32_bf16(fah[mi], fbl[ni], acc[mi][ni], 0, 0, 0);
      }
  }

#pragma unroll
  for (int ni = 0; ni < FN; ++ni) {
    const int col = n0 + wn * HN + ni * 16 + l16;
    const float b1 = bias[col];
#pragma unroll
    for (int mi = 0; mi < FM; ++mi)
#pragma unroll
      for (int r = 0; r < 4; ++r) {
        const int row = m0 + wm * HM + mi * 16 + quad * 4 + r;
        float v = acc[mi][ni][r] + b1;
        if constexpr (EPI == 0) {
          Cf[(size_t)row * N + col] = v;
        } else if constexpr (EPI == 2) {
          C16[(size_t)row * N + col] = f2bf(v);
        } else if constexpr (EPI == 4) {
          const float m = bf2f(mod16[(size_t)row * N + col]);
          C16[(size_t)row * N + col] = f2bf(v * m * sc);
        } else if constexpr (EPI == 6) {
          v = fmaxf(v, 0.f);
          unsigned short h, l;
          split1(v, h, l);
          CH[(size_t)row * N + col] = h;
          CL[(size_t)row * N + col] = l;
        } else {
          C16[(size_t)row * N + col] = f2bf(1.f / (1.f + __expf(-v)));
        }
      }
  }
}

// ------------- V transpose: bf16 [B*S, D] -> bf16 [B, H, HD, S] -------------
__global__ __launch_bounds__(256)
void vtrans_kernel(const unsigned short* __restrict__ V16, unsigned short* __restrict__ Vt)
{
  __shared__ unsigned short T[64][72];
  const int x  = blockIdx.x;
  const int st = x & 31;
  const int h  = (x >> 5) & 7;
  const int b  = x >> 8;
  const int t  = threadIdx.x;
  const unsigned short* src = V16 + ((size_t)b * SS + st * 64) * DD + h * HDIM;
  for (int i = t; i < 1024; i += 256) {
    int r = i >> 4, c4 = (i & 15) * 4;
    *(ushort4*)&T[r][c4] = *(const ushort4*)&src[(size_t)r * DD + c4];
  }
  __syncthreads();
  unsigned short* dst = Vt + ((size_t)(b * HH + h) * HDIM) * SS + st * 64;
  for (int i = t; i < 1024; i += 256) {
    int hd = i >> 4, s4 = (i & 15) * 4;
    ushort4 u = make_ushort4(T[s4 + 0][hd], T[s4 + 1][hd], T[s4 + 2][hd], T[s4 + 3][hd]);
    *(ushort4*)&dst[(size_t)hd * SS + s4] = u;
  }
}

// ------------- barrier-free two-pass flash attention -------------
// K/V/Q fragments gathered straight from L2 (head-grouped XCD swizzle makes the
// per-XCD working set ~3MB < 4MB L2). Only Ps (wave-private) lives in LDS.
// No __syncthreads anywhere. scale 1/8 pre-folded into q16.
__global__ __launch_bounds__(256)
void attn_kernel(const unsigned short* __restrict__ Q16,
                 const unsigned short* __restrict__ K16,
                 const unsigned short* __restrict__ Vt,
                 float* __restrict__ AW, float* __restrict__ AO)
{
  __shared__ alignas(16) unsigned short Ps[4][16][64];

  const int t    = threadIdx.x;
  const int wid  = t >> 6;
  const int lane = t & 63;
  const int quad = lane >> 4;
  const int l16  = lane & 15;
  // head-grouped block remap: all 32 q-blocks of head g land on XCD g&7
  const int x  = blockIdx.x;
  const int j  = x >> 3;
  const int g  = ((j >> 5) << 3) | (x & 7);
  const int qb = j & 31;
  const int b  = g >> 3;
  const int h  = g & 7;
  const int q0 = qb * 64;

  const unsigned short* Qg = Q16 + ((size_t)b * SS + q0) * DD + h * HDIM;
  const unsigned short* Kg = K16 + (size_t)b * SS * DD + h * HDIM;
  const unsigned short* Vg = Vt + ((size_t)(b * HH + h) * HDIM) * SS;

  // Q fragments straight to registers
  const bf16x8 a0 = *(const bf16x8*)&Qg[(size_t)(wid * 16 + l16) * DD + quad * 8];
  const bf16x8 a1 = *(const bf16x8*)&Qg[(size_t)(wid * 16 + l16) * DD + 32 + quad * 8];

  // ---- Pass A: l = sum_k exp(s) (no max; scores O(1) by construction) ----
  float lsum[4] = {0.f, 0.f, 0.f, 0.f};
  for (int kt = 0; kt < SS / 64; ++kt) {
#pragma unroll
    for (int kst = 0; kst < 4; ++kst) {
      const unsigned short* kr = Kg + (size_t)(kt * 64 + kst * 16 + l16) * DD + quad * 8;
      bf16x8 bb0 = *(const bf16x8*)kr;
      bf16x8 bb1 = *(const bf16x8*)(kr + 32);
      floatx4 cc = {0.f, 0.f, 0.f, 0.f};
      cc = __builtin_amdgcn_mfma_f32_16x16x32_bf16(a0, bb0, cc, 0, 0, 0);
      cc = __builtin_amdgcn_mfma_f32_16x16x32_bf16(a1, bb1, cc, 0, 0, 0);
#pragma unroll
      for (int r = 0; r < 4; ++r) lsum[r] += __expf(cc[r]);
    }
  }
#pragma unroll
  for (int r = 0; r < 4; ++r) {
    float v = lsum[r];
    v += __shfl_xor(v, 1, 64); v += __shfl_xor(v, 2, 64);
    v += __shfl_xor(v, 4, 64); v += __shfl_xor(v, 8, 64);
    lsum[r] = 1.f / v;          // now inv_l
  }

  floatx4 o[4];
#pragma unroll
  for (int n = 0; n < 4; ++n) { floatx4 z = {0.f, 0.f, 0.f, 0.f}; o[n] = z; }

  const size_t awb = ((size_t)(b * HH + h) * SS + q0 + wid * 16) * SS;

  // ---- Pass B: recompute, write normalized weights, accumulate PV ----
  for (int kt = 0; kt < SS / 64; ++kt) {
#pragma unroll
    for (int kst = 0; kst < 4; ++kst) {
      const unsigned short* kr = Kg + (size_t)(kt * 64 + kst * 16 + l16) * DD + quad * 8;
      bf16x8 bb0 = *(const bf16x8*)kr;
      bf16x8 bb1 = *(const bf16x8*)(kr + 32);
      floatx4 cc = {0.f, 0.f, 0.f, 0.f};
      cc = __builtin_amdgcn_mfma_f32_16x16x32_bf16(a0, bb0, cc, 0, 0, 0);
      cc = __builtin_amdgcn_mfma_f32_16x16x32_bf16(a1, bb1, cc, 0, 0, 0);
#pragma unroll
      for (int r = 0; r < 4; ++r) {
        const float wv = __expf(cc[r]) * lsum[r];
        Ps[wid][quad * 4 + r][SWZ(quad * 4 + r, kst * 16 + l16)] = f2bf(wv);
      }
    }
    // coalesced AW write via Ps readback (wave-private LDS, in-order per wave)
    for (int i = lane; i < 256; i += 64) {
      const int q = i >> 4, k4 = (i & 15) * 4;
      ushort4 u = *(const ushort4*)&Ps[wid][q][SWZ(q, k4)];
      float4 f = make_float4(bf2f(u.x), bf2f(u.y), bf2f(u.z), bf2f(u.w));
      *(float4*)&AW[awb + (size_t)q * SS + kt * 64 + k4] = f;
    }
    // PV: A = P[q][key] (LDS), B = V^T[hd][key] gathered from L2
#pragma unroll
    for (int c2 = 0; c2 < 2; ++c2) {
      bf16x8 ap = *(const bf16x8*)&Ps[wid][l16][SWZ(l16, c2 * 32 + quad * 8)];
#pragma unroll
      for (int n = 0; n < 4; ++n) {
        bf16x8 bv = *(const bf16x8*)&Vg[(size_t)(n * 16 + l16) * SS + kt * 64 + c2 * 32 + quad * 8];
        o[n] = __builtin_amdgcn_mfma_f32_16x16x32_bf16(ap, bv, o[n], 0, 0, 0);
      }
    }
  }
  float* AOg = AO + ((size_t)b * SS + q0 + wid * 16) * DD + h * HDIM;
#pragma unroll
  for (int n = 0; n < 4; ++n)
#pragma unroll
    for (int r = 0; r < 4; ++r)
      AOg[(size_t)(quad * 4 + r) * DD + n * 16 + l16] = o[n][r];
}

extern "C" void kernel_launch(void* const* d_in, const int* in_sizes, int n_in,
                              void* d_out, int out_size, void* d_ws, size_t ws_size,
                              hipStream_t stream) {
  (void)in_sizes; (void)n_in; (void)out_size; (void)ws_size;
  const float* query = (const float*)d_in[0];
  const float* key_i = (const float*)d_in[1];
  const float* value = (const float*)d_in[2];
  const float* Wq  = (const float*)d_in[3];
  const float* bq  = (const float*)d_in[4];
  const float* Wk  = (const float*)d_in[5];
  const float* bk  = (const float*)d_in[6];
  const float* Wv  = (const float*)d_in[7];
  const float* bv  = (const float*)d_in[8];
  const float* Wo  = (const float*)d_in[9];
  const float* bo  = (const float*)d_in[10];
  const float* Wg  = (const float*)d_in[11];
  const float* bg  = (const float*)d_in[12];
  const float* Wmq = (const float*)d_in[13];
  const float* bmq = (const float*)d_in[14];
  const float* Wmk = (const float*)d_in[15];
  const float* bmk = (const float*)d_in[16];

  float* out = (float*)d_out;
  float* AW  = out + (size_t)BB * SS * DD;    // attn_weights at float offset 4,194,304

  // out region [0,16MB) is dead until the last GEMM -> park vt and q16 there:
  unsigned short* vt  = (unsigned short*)out;                 // [0,8MB)
  unsigned short* q16 = (unsigned short*)out + 4194304;       // [8,16MB)

  // workspace (49 MiB peak, proven footprint):
  //  [0,5)   weight planes
  //  [5,21)  P: activation hi/lo planes, reused query->key->value->ao
  //  [21,25) lat planes (hi/lo bf16 [8192,128])
  //  [25,33) mod bf16 (modq then modk)      } ao fp32 [25,41) overlays both
  //  [33,41) v16 bf16                        } (dead before attn writes ao)
  //  [41,49) k16 bf16
  char* ws = (char*)d_ws;
  unsigned short* ws16 = (unsigned short*)ws;
  unsigned short* PH   = (unsigned short*)(ws + (5u  << 20));
  unsigned short* PL   = (unsigned short*)(ws + (13u << 20));
  unsigned short* latH = (unsigned short*)(ws + (21u << 20));
  unsigned short* latL = (unsigned short*)(ws + (23u << 20));
  unsigned short* mod  = (unsigned short*)(ws + (25u << 20));
  unsigned short* v16  = (unsigned short*)(ws + (33u << 20));
  float*          ao   = (float*)(ws + (25u << 20));
  unsigned short* k16  = (unsigned short*)(ws + (41u << 20));

  const size_t W_WQH = 0,       W_WQL = 262144;
  const size_t W_WKH = 524288,  W_WKL = 786432;
  const size_t W_WVH = 1048576, W_WVL = 1310720;
  const size_t W_WOH = 1572864, W_WOL = 1835008;
  const size_t W_WGH = 2097152, W_WGL = 2162688;
  const size_t W_WMQH = 2228224, W_WMQL = 2293760;
  const size_t W_WMKH = 2359296, W_WMKL = 2424832;

  dim3 blk(256);
  // 0. weight transpose + hi/lo split
  wsplit_kernel<<<dim3(304), blk, 0, stream>>>(Wq, Wk, Wv, Wo, Wg, Wmq, Wmk, ws16);
  // 1. query -> planes
  asplit_kernel<<<dim3(2048), blk, 0, stream>>>(query, PH, PL);
  // 2. lat planes = split(relu(query @ Wg + bg))
  mgemm_kernel<64, 64, 6, false><<<dim3(2, 128), blk, 0, stream>>>(
      PH, PL, ws16 + W_WGH, ws16 + W_WGL, bg, nullptr, 1.f,
      nullptr, nullptr, latH, latL, 512, 128);
  // 3. mod = bf16(sigmoid(lat @ Wmq + bmq))
  mgemm_kernel<64, 64, 7, false><<<dim3(8, 128), blk, 0, stream>>>(
      latH, latL, ws16 + W_WMQH, ws16 + W_WMQL, bmq, nullptr, 1.f,
      nullptr, mod, nullptr, nullptr, 128, 512);
  // 4. q16 = bf16((query @ Wq + bq) * mod * 0.125)
  mgemm_kernel<128, 64, 4, true><<<dim3(512), blk, 0, stream>>>(
      PH, PL, ws16 + W_WQH, ws16 + W_WQL, bq, mod, 0.125f,
      nullptr, q16, nullptr, nullptr, 512, 512);
  // 5. key -> planes (query planes dead)
  asplit_kernel<<<dim3(2048), blk, 0, stream>>>(key_i, PH, PL);
  // 6. mod = bf16(sigmoid(lat @ Wmk + bmk))
  mgemm_kernel<64, 64, 7, false><<<dim3(8, 128), blk, 0, stream>>>(
      latH, latL, ws16 + W_WMKH, ws16 + W_WMKL, bmk, nullptr, 1.f,
      nullptr, mod, nullptr, nullptr, 128, 512);
  // 7. k16 = bf16((key @ Wk + bk) * mod)
  mgemm_kernel<128, 64, 4, true><<<dim3(512), blk, 0, stream>>>(
      PH, PL, ws16 + W_WKH, ws16 + W_WKL, bk, mod, 1.f,
      nullptr, k16, nullptr, nullptr, 512, 512);
  // 8. value -> planes
  asplit_kernel<<<dim3(2048), blk, 0, stream>>>(value, PH, PL);
  // 9. v16 = bf16(value @ Wv + bv)
  mgemm_kernel<128, 64, 2, true><<<dim3(512), blk, 0, stream>>>(
      PH, PL, ws16 + W_WVH, ws16 + W_WVL, bv, nullptr, 1.f,
      nullptr, v16, nullptr, nullptr, 512, 512);
  // 10. V^T per (b,h)  (vt lives in out region)
  vtrans_kernel<<<dim3(1024), blk, 0, stream>>>(v16, vt);
  // 11. attention: AW -> out tail, ao -> ws (mod/v16 dead)
  attn_kernel<<<dim3(1024), blk, 0, stream>>>(q16, k16, vt, AW, ao);
  // 12. ao -> planes
  asplit_kernel<<<dim3(2048), blk, 0, stream>>>(ao, PH, PL);
  // 13. out = ao @ Wo + bo  (overwrites vt/q16 scratch)
  mgemm_kernel<128, 64, 0, true><<<dim3(512), blk, 0, stream>>>(
      PH, PL, ws16 + W_WOH, ws16 + W_WOL, bo, nullptr, 1.f,
      out, nullptr, nullptr, nullptr, 512, 512);
}

// Round 4
// 853.966 us; speedup vs baseline: 1.2366x; 1.2366x over previous
//
#include <hip/hip_runtime.h>
#include <hip/hip_bf16.h>

#define BB 4
#define SS 2048
#define DD 512
#define HH 8
#define HDIM 64

typedef __attribute__((ext_vector_type(8))) short bf16x8;
typedef __attribute__((ext_vector_type(4))) float floatx4;
typedef __attribute__((ext_vector_type(8))) unsigned short u16x8;

static __device__ __forceinline__ unsigned short f2bf(float x) {
  __hip_bfloat16 h = __float2bfloat16(x);
  unsigned short u;
  __builtin_memcpy(&u, &h, sizeof(u));
  return u;
}
static __device__ __forceinline__ float bf2f(unsigned short u) {
  union { unsigned int i; float f; } c;
  c.i = ((unsigned int)u) << 16;
  return c.f;
}
static __device__ __forceinline__ void split1(float x, unsigned short& h, unsigned short& l) {
  h = f2bf(x);
  l = f2bf(x - bf2f(h));     // exact residual, second bf16 term
}
static __device__ __forceinline__ void gload_lds16(const void* g, void* l) {
  __builtin_amdgcn_global_load_lds((const __attribute__((address_space(1))) void*)g,
                                   (__attribute__((address_space(3))) void*)l, 16, 0, 0);
}

// LDS XOR swizzle for 128B-stride rows (granularity: 8 ushorts = 16B)
#define SWZ(row, col) ((col) ^ (((row) & 7) * 8))

// Stage a 64x64 ushort tile global->LDS via global_load_lds, with pre-swizzled
// source so that LDS[row][c] = G[row][c ^ ((row&7)*8)] (SWZ-consistent reads).
static __device__ __forceinline__ void stage_tile(unsigned short* dst,
    const unsigned short* src, size_t rstride, int wid, int lane) {
#pragma unroll
  for (int it = 0; it < 2; ++it) {
    const int base = it * 256 + wid * 64;      // wave-uniform 1KB chunk
    const int c = base + lane;                  // 16B unit id, 512 total
    const int row = c >> 3, uu = c & 7;
    gload_lds16(src + (size_t)row * rstride + ((uu ^ (row & 7)) * 8),
                dst + (size_t)base * 8);
  }
}

// ---------------- weight transpose + hi/lo bf16 split ----------------
__global__ __launch_bounds__(256)
void wsplit_kernel(const float* __restrict__ Wq, const float* __restrict__ Wk,
                   const float* __restrict__ Wv, const float* __restrict__ Wo,
                   const float* __restrict__ Wg, const float* __restrict__ Wmq,
                   const float* __restrict__ Wmk, unsigned short* __restrict__ wsb)
{
  const int bx = blockIdx.x;
  const float* src; unsigned short* dh; unsigned short* dl; int K, N, tile;
  if (bx < 64)       { src = Wq;  dh = wsb + 0;       dl = wsb + 262144;  K = 512; N = 512; tile = bx; }
  else if (bx < 128) { src = Wk;  dh = wsb + 524288;  dl = wsb + 786432;  K = 512; N = 512; tile = bx - 64; }
  else if (bx < 192) { src = Wv;  dh = wsb + 1048576; dl = wsb + 1310720; K = 512; N = 512; tile = bx - 128; }
  else if (bx < 256) { src = Wo;  dh = wsb + 1572864; dl = wsb + 1835008; K = 512; N = 512; tile = bx - 192; }
  else if (bx < 272) { src = Wg;  dh = wsb + 2097152; dl = wsb + 2162688; K = 512; N = 128; tile = bx - 256; }
  else if (bx < 288) { src = Wmq; dh = wsb + 2228224; dl = wsb + 2293760; K = 128; N = 512; tile = bx - 272; }
  else               { src = Wmk; dh = wsb + 2359296; dl = wsb + 2424832; K = 128; N = 512; tile = bx - 288; }
  const int nt = N >> 6;
  const int k0 = (tile / nt) * 64, n0 = (tile % nt) * 64;
  __shared__ float T[64][65];
  const int t = threadIdx.x;
  const int r = t >> 2, c = (t & 3) * 16;
#pragma unroll
  for (int j = 0; j < 16; j += 4)
    *(float4*)&T[r][c + j] = *(const float4*)&src[(size_t)(k0 + r) * N + n0 + c + j];
  __syncthreads();
  u16x8 hv[2], lv[2];
#pragma unroll
  for (int j = 0; j < 16; ++j) {
    unsigned short h, l;
    split1(T[c + j][r], h, l);
    hv[j >> 3][j & 7] = h;
    lv[j >> 3][j & 7] = l;
  }
  const size_t di = (size_t)(n0 + r) * K + k0 + c;
  *(u16x8*)&dh[di]     = hv[0];
  *(u16x8*)&dh[di + 8] = hv[1];
  *(u16x8*)&dl[di]     = lv[0];
  *(u16x8*)&dl[di + 8] = lv[1];
}

// ---------------- 3-term split-bf16 MFMA GEMM phase (on-the-fly A split) ----------------
template<int BM, int BN>
static __device__ __forceinline__ void gemm_phase(
    const float* __restrict__ A, const unsigned short* __restrict__ WHp,
    const unsigned short* __restrict__ WLp, const int K,
    const int m0, const int n0,
    unsigned short (*Ah)[32], unsigned short (*Al)[32],
    unsigned short (*Bh)[32], unsigned short (*Bl)[32],
    floatx4 (*acc)[BN / 32])
{
  constexpr int HM = BM / 2, HN = BN / 2, FM = BM / 32, FN = BN / 32;
  constexpr int TPR = 256 / BM;
  constexpr int CPT = 32 / TPR;
  constexpr int WCH = BN / 16;
  constexpr int WPW = (2 * WCH) / 4;
  const int t = threadIdx.x;
  const int wid = t >> 6, lane = t & 63, quad = lane >> 4, l16 = lane & 15;
  const int wm = wid >> 1, wn = wid & 1;
  const int arow = t / TPR, acol = (t % TPR) * CPT;
  const int asw = (arow & 3) * 8;

  for (int k0 = 0; k0 < K; k0 += 32) {
    __syncthreads();
#pragma unroll
    for (int cc = 0; cc < WPW; ++cc) {
      const int cid = wid * WPW + cc;
      const int pl = cid / WCH, ch = cid - pl * WCH;
      const int row = ch * 16 + (lane >> 2);
      const int kof = ((lane & 3) ^ ((lane >> 2) & 3)) * 8;
      const unsigned short* g = (pl ? WLp : WHp) + (size_t)(n0 + row) * K + k0 + kof;
      gload_lds16(g, (pl ? Bl : Bh)[ch * 16]);
    }
    {
      const float* ga = A + (size_t)(m0 + arow) * K + k0 + acol;
#pragma unroll
      for (int j = 0; j < CPT; j += 4) {
        float4 f = *(const float4*)(ga + j);
        unsigned short h[4], l[4];
        split1(f.x, h[0], l[0]); split1(f.y, h[1], l[1]);
        split1(f.z, h[2], l[2]); split1(f.w, h[3], l[3]);
        *(ushort4*)&Ah[arow][(acol + j) ^ asw] = make_ushort4(h[0], h[1], h[2], h[3]);
        *(ushort4*)&Al[arow][(acol + j) ^ asw] = make_ushort4(l[0], l[1], l[2], l[3]);
      }
    }
    __syncthreads();
    const int swf = (l16 & 3) * 8;
    bf16x8 fah[FM], fal[FM], fbh[FN], fbl[FN];
#pragma unroll
    for (int mi = 0; mi < FM; ++mi) {
      const int rr = wm * HM + mi * 16 + l16;
      fah[mi] = *(const bf16x8*)&Ah[rr][(quad * 8) ^ swf];
      fal[mi] = *(const bf16x8*)&Al[rr][(quad * 8) ^ swf];
    }
#pragma unroll
    for (int ni = 0; ni < FN; ++ni) {
      const int rr = wn * HN + ni * 16 + l16;
      fbh[ni] = *(const bf16x8*)&Bh[rr][(quad * 8) ^ swf];
      fbl[ni] = *(const bf16x8*)&Bl[rr][(quad * 8) ^ swf];
    }
#pragma unroll
    for (int mi = 0; mi < FM; ++mi)
#pragma unroll
      for (int ni = 0; ni < FN; ++ni) {
        acc[mi][ni] = __builtin_amdgcn_mfma_f32_16x16x32_bf16(fah[mi], fbh[ni], acc[mi][ni], 0, 0, 0);
        acc[mi][ni] = __builtin_amdgcn_mfma_f32_16x16x32_bf16(fal[mi], fbh[ni], acc[mi][ni], 0, 0, 0);
        acc[mi][ni] = __builtin_amdgcn_mfma_f32_16x16x32_bf16(fah[mi], fbl[ni], acc[mi][ni], 0, 0, 0);
      }
  }
}

// EPI: 0 fp32 | 1 relu fp32 | 2 bf16 | 4 bf16*(mod*sc) | 5 sigmoid fp32
template<int BM, int BN, int EPI>
__global__ __launch_bounds__(256, 2)
void mgemm_kernel(const float* __restrict__ A, const unsigned short* __restrict__ WH,
                  const unsigned short* __restrict__ WL, const float* __restrict__ bias,
                  const float* __restrict__ modf, const float sc,
                  float* __restrict__ Cf, unsigned short* __restrict__ C16,
                  int K, int N)
{
  constexpr int HM = BM / 2, HN = BN / 2, FM = BM / 32, FN = BN / 32;
  __shared__ alignas(16) unsigned short Ah[BM][32], Al[BM][32], Bh[BN][32], Bl[BN][32];
  const int t = threadIdx.x;
  const int wid = t >> 6, lane = t & 63, quad = lane >> 4, l16 = lane & 15;
  const int wm = wid >> 1, wn = wid & 1;
  const int m0 = blockIdx.y * BM, n0 = blockIdx.x * BN;

  floatx4 acc[FM][FN];
#pragma unroll
  for (int i = 0; i < FM; ++i)
#pragma unroll
    for (int j = 0; j < FN; ++j) {
      floatx4 z = {0.f, 0.f, 0.f, 0.f};
      acc[i][j] = z;
    }

  gemm_phase<BM, BN>(A, WH, WL, K, m0, n0, Ah, Al, Bh, Bl, acc);

#pragma unroll
  for (int ni = 0; ni < FN; ++ni) {
    const int col = n0 + wn * HN + ni * 16 + l16;
    const float b1 = bias[col];
#pragma unroll
    for (int mi = 0; mi < FM; ++mi)
#pragma unroll
      for (int r = 0; r < 4; ++r) {
        const int row = m0 + wm * HM + mi * 16 + quad * 4 + r;
        float v = acc[mi][ni][r] + b1;
        if constexpr (EPI == 0) {
          Cf[(size_t)row * N + col] = v;
        } else if constexpr (EPI == 1) {
          Cf[(size_t)row * N + col] = fmaxf(v, 0.f);
        } else if constexpr (EPI == 2) {
          C16[(size_t)row * N + col] = f2bf(v);
        } else if constexpr (EPI == 4) {
          const float m = modf[(size_t)row * N + col];
          C16[(size_t)row * N + col] = f2bf(v * m * sc);
        } else {
          Cf[(size_t)row * N + col] = 1.f / (1.f + __expf(-v));
        }
      }
  }
}

// ------------- V transpose: bf16 [B*S, D] -> bf16 [B, H, HD, S] -------------
__global__ __launch_bounds__(256)
void vtrans_kernel(const unsigned short* __restrict__ V16, unsigned short* __restrict__ Vt)
{
  __shared__ unsigned short T[64][72];
  const int x  = blockIdx.x;
  const int st = x & 31;
  const int h  = (x >> 5) & 7;
  const int b  = x >> 8;
  const int t  = threadIdx.x;
  const unsigned short* src = V16 + ((size_t)b * SS + st * 64) * DD + h * HDIM;
  for (int i = t; i < 1024; i += 256) {
    int r = i >> 4, c4 = (i & 15) * 4;
    *(ushort4*)&T[r][c4] = *(const ushort4*)&src[(size_t)r * DD + c4];
  }
  __syncthreads();
  unsigned short* dst = Vt + ((size_t)(b * HH + h) * HDIM) * SS + st * 64;
  for (int i = t; i < 1024; i += 256) {
    int hd = i >> 4, s4 = (i & 15) * 4;
    ushort4 u = make_ushort4(T[s4 + 0][hd], T[s4 + 1][hd], T[s4 + 2][hd], T[s4 + 3][hd]);
    *(ushort4*)&dst[(size_t)hd * SS + s4] = u;
  }
}

// ------------- attention pass A: partial softmax denominators -------------
// grid = 4096 = 4 key-chunks x 1024 (head-grouped). Each block: 64 q x 512 keys.
// lsum4[g*SS+row][c] = sum over chunk c's 512 keys of exp(q.k)  (scale folded in q16)
__global__ __launch_bounds__(256)
void attn_lsum_kernel(const unsigned short* __restrict__ Q16,
                      const unsigned short* __restrict__ K16,
                      float* __restrict__ lsum4)
{
  __shared__ alignas(16) unsigned short Ks[2][64][64];
  const int t = threadIdx.x, wid = t >> 6, lane = t & 63;
  const int quad = lane >> 4, l16 = lane & 15;
  const int x = blockIdx.x;
  const int c = x >> 10;             // key chunk 0..3
  const int y = x & 1023;            // head-grouped mapping (XCD = y&7)
  const int j = y >> 3;
  const int g = ((j >> 5) << 3) | (y & 7);
  const int qb = j & 31;
  const int b = g >> 3, h = g & 7;
  const int q0 = qb * 64;

  const unsigned short* Qg = Q16 + ((size_t)b * SS + q0) * DD + h * HDIM;
  const unsigned short* Kg = K16 + (size_t)b * SS * DD + h * HDIM + (size_t)c * 512 * DD;

  const bf16x8 a0 = *(const bf16x8*)&Qg[(size_t)(wid * 16 + l16) * DD + quad * 8];
  const bf16x8 a1 = *(const bf16x8*)&Qg[(size_t)(wid * 16 + l16) * DD + 32 + quad * 8];

  stage_tile(&Ks[0][0][0], Kg, DD, wid, lane);
  __syncthreads();

  float lsum[4] = {0.f, 0.f, 0.f, 0.f};
  for (int kt = 0; kt < 8; ++kt) {
    const int cur = kt & 1;
    if (kt < 7)
      stage_tile(&Ks[cur ^ 1][0][0], Kg + (size_t)(kt + 1) * 64 * DD, DD, wid, lane);
#pragma unroll
    for (int kst = 0; kst < 4; ++kst) {
      bf16x8 bb0 = *(const bf16x8*)&Ks[cur][kst * 16 + l16][SWZ(l16, quad * 8)];
      bf16x8 bb1 = *(const bf16x8*)&Ks[cur][kst * 16 + l16][SWZ(l16, 32 + quad * 8)];
      floatx4 cc = {0.f, 0.f, 0.f, 0.f};
      cc = __builtin_amdgcn_mfma_f32_16x16x32_bf16(a0, bb0, cc, 0, 0, 0);
      cc = __builtin_amdgcn_mfma_f32_16x16x32_bf16(a1, bb1, cc, 0, 0, 0);
#pragma unroll
      for (int r = 0; r < 4; ++r) lsum[r] += __expf(cc[r]);
    }
    __syncthreads();
  }
#pragma unroll
  for (int r = 0; r < 4; ++r) {
    float v = lsum[r];
    v += __shfl_xor(v, 1, 64); v += __shfl_xor(v, 2, 64);
    v += __shfl_xor(v, 4, 64); v += __shfl_xor(v, 8, 64);
    if (l16 == 0)
      lsum4[((size_t)g * SS + q0 + wid * 16 + quad * 4 + r) * 4 + c] = v;
  }
}

// ------------- attention pass B: weights + PV, single K/V sweep -------------
// grid = 1024 (head-grouped). LDS 40KB -> 4 blocks/CU.
__global__ __launch_bounds__(256)
void attn_pv_kernel(const unsigned short* __restrict__ Q16,
                    const unsigned short* __restrict__ K16,
                    const unsigned short* __restrict__ Vt,
                    const float* __restrict__ lsum4,
                    float* __restrict__ AW, float* __restrict__ AO)
{
  __shared__ alignas(16) unsigned short Ks[2][64][64];
  __shared__ alignas(16) unsigned short Vs[2][64][64];
  __shared__ alignas(16) unsigned short Ps[4][16][64];

  const int t = threadIdx.x, wid = t >> 6, lane = t & 63;
  const int quad = lane >> 4, l16 = lane & 15;
  const int x = blockIdx.x;
  const int j = x >> 3;
  const int g = ((j >> 5) << 3) | (x & 7);
  const int qb = j & 31;
  const int b = g >> 3, h = g & 7;
  const int q0 = qb * 64;

  const unsigned short* Qg = Q16 + ((size_t)b * SS + q0) * DD + h * HDIM;
  const unsigned short* Kg = K16 + (size_t)b * SS * DD + h * HDIM;
  const unsigned short* Vg = Vt + ((size_t)(b * HH + h) * HDIM) * SS;

  const bf16x8 a0 = *(const bf16x8*)&Qg[(size_t)(wid * 16 + l16) * DD + quad * 8];
  const bf16x8 a1 = *(const bf16x8*)&Qg[(size_t)(wid * 16 + l16) * DD + 32 + quad * 8];

  float inv_l[4];
#pragma unroll
  for (int r = 0; r < 4; ++r) {
    float4 lv = *(const float4*)&lsum4[((size_t)g * SS + q0 + wid * 16 + quad * 4 + r) * 4];
    inv_l[r] = 1.f / (lv.x + lv.y + lv.z + lv.w);
  }

  stage_tile(&Ks[0][0][0], Kg, DD, wid, lane);
  stage_tile(&Vs[0][0][0], Vg, SS, wid, lane);
  __syncthreads();

  floatx4 o[4];
#pragma unroll
  for (int n = 0; n < 4; ++n) { floatx4 z = {0.f, 0.f, 0.f, 0.f}; o[n] = z; }

  const size_t awb = ((size_t)g * SS + q0 + wid * 16) * SS;

  for (int kt = 0; kt < SS / 64; ++kt) {
    const int cur = kt & 1;
    if (kt < 31) {
      stage_tile(&Ks[cur ^ 1][0][0], Kg + (size_t)(kt + 1) * 64 * DD, DD, wid, lane);
      stage_tile(&Vs[cur ^ 1][0][0], Vg + (size_t)(kt + 1) * 64, SS, wid, lane);
    }
#pragma unroll
    for (int kst = 0; kst < 4; ++kst) {
      bf16x8 bb0 = *(const bf16x8*)&Ks[cur][kst * 16 + l16][SWZ(l16, quad * 8)];
      bf16x8 bb1 = *(const bf16x8*)&Ks[cur][kst * 16 + l16][SWZ(l16, 32 + quad * 8)];
      floatx4 cc = {0.f, 0.f, 0.f, 0.f};
      cc = __builtin_amdgcn_mfma_f32_16x16x32_bf16(a0, bb0, cc, 0, 0, 0);
      cc = __builtin_amdgcn_mfma_f32_16x16x32_bf16(a1, bb1, cc, 0, 0, 0);
#pragma unroll
      for (int r = 0; r < 4; ++r) {
        const float wv = __expf(cc[r]) * inv_l[r];
        AW[awb + (size_t)(quad * 4 + r) * SS + kt * 64 + kst * 16 + l16] = wv;
        Ps[wid][quad * 4 + r][SWZ(quad * 4 + r, kst * 16 + l16)] = f2bf(wv);
      }
    }
    // PV: A = P[q][key] (wave-private LDS), B = V^T[hd][key]
#pragma unroll
    for (int c2 = 0; c2 < 2; ++c2) {
      bf16x8 ap = *(const bf16x8*)&Ps[wid][l16][SWZ(l16, c2 * 32 + quad * 8)];
#pragma unroll
      for (int n = 0; n < 4; ++n) {
        bf16x8 bv = *(const bf16x8*)&Vs[cur][n * 16 + l16][SWZ(l16, c2 * 32 + quad * 8)];
        o[n] = __builtin_amdgcn_mfma_f32_16x16x32_bf16(ap, bv, o[n], 0, 0, 0);
      }
    }
    __syncthreads();
  }
  float* AOg = AO + ((size_t)b * SS + q0 + wid * 16) * DD + h * HDIM;
#pragma unroll
  for (int n = 0; n < 4; ++n)
#pragma unroll
    for (int r = 0; r < 4; ++r)
      AOg[(size_t)(quad * 4 + r) * DD + n * 16 + l16] = o[n][r];
}

extern "C" void kernel_launch(void* const* d_in, const int* in_sizes, int n_in,
                              void* d_out, int out_size, void* d_ws, size_t ws_size,
                              hipStream_t stream) {
  (void)in_sizes; (void)n_in; (void)out_size; (void)ws_size;
  const float* query = (const float*)d_in[0];
  const float* key_i = (const float*)d_in[1];
  const float* value = (const float*)d_in[2];
  const float* Wq  = (const float*)d_in[3];
  const float* bq  = (const float*)d_in[4];
  const float* Wk  = (const float*)d_in[5];
  const float* bk  = (const float*)d_in[6];
  const float* Wv  = (const float*)d_in[7];
  const float* bv  = (const float*)d_in[8];
  const float* Wo  = (const float*)d_in[9];
  const float* bo  = (const float*)d_in[10];
  const float* Wg  = (const float*)d_in[11];
  const float* bg  = (const float*)d_in[12];
  const float* Wmq = (const float*)d_in[13];
  const float* bmq = (const float*)d_in[14];
  const float* Wmk = (const float*)d_in[15];
  const float* bmk = (const float*)d_in[16];

  float* out = (float*)d_out;
  float* AW  = out + (size_t)BB * SS * DD;

  // workspace (50 MiB):
  //  [0,5)   weight planes
  //  [5,13)  q16 bf16   [13,21) k16 bf16   [21,29) vt bf16
  //  [29,33) lat fp32
  //  [33,49) X region, time-shared: modq -> modk -> v16 -> ao
  //  [49,50) lsum4 fp32 [B*H*S][4]
  char* ws = (char*)d_ws;
  unsigned short* ws16 = (unsigned short*)ws;
  unsigned short* q16 = (unsigned short*)(ws + (5u  << 20));
  unsigned short* k16 = (unsigned short*)(ws + (13u << 20));
  unsigned short* vt  = (unsigned short*)(ws + (21u << 20));
  float*          lat = (float*)(ws + (29u << 20));
  float*          X   = (float*)(ws + (33u << 20));
  unsigned short* v16 = (unsigned short*)(ws + (33u << 20));
  float*          ao  = (float*)(ws + (33u << 20));
  float*          lsum4 = (float*)(ws + (49u << 20));

  const size_t W_WQH = 0,       W_WQL = 262144;
  const size_t W_WKH = 524288,  W_WKL = 786432;
  const size_t W_WVH = 1048576, W_WVL = 1310720;
  const size_t W_WOH = 1572864, W_WOL = 1835008;
  const size_t W_WGH = 2097152, W_WGL = 2162688;
  const size_t W_WMQH = 2228224, W_WMQL = 2293760;
  const size_t W_WMKH = 2359296, W_WMKL = 2424832;

  dim3 blk(256);
  // 0. weight transpose + hi/lo split
  wsplit_kernel<<<dim3(304), blk, 0, stream>>>(Wq, Wk, Wv, Wo, Wg, Wmq, Wmk, ws16);
  // 1. lat = relu(query @ Wg + bg)
  mgemm_kernel<64, 64, 1><<<dim3(2, 128), blk, 0, stream>>>(
      query, ws16 + W_WGH, ws16 + W_WGL, bg, nullptr, 1.f, lat, nullptr, 512, 128);
  // 2. modq = sigmoid(lat @ Wmq + bmq)   (fp32 -> X)
  mgemm_kernel<64, 64, 5><<<dim3(8, 128), blk, 0, stream>>>(
      lat, ws16 + W_WMQH, ws16 + W_WMQL, bmq, nullptr, 1.f, X, nullptr, 128, 512);
  // 3. q16 = bf16((query @ Wq + bq) * modq * 0.125)   (attn scale folded in)
  mgemm_kernel<128, 64, 4><<<dim3(8, 64), blk, 0, stream>>>(
      query, ws16 + W_WQH, ws16 + W_WQL, bq, X, 0.125f, nullptr, q16, 512, 512);
  // 4. modk = sigmoid(lat @ Wmk + bmk)   (fp32 -> X, modq dead)
  mgemm_kernel<64, 64, 5><<<dim3(8, 128), blk, 0, stream>>>(
      lat, ws16 + W_WMKH, ws16 + W_WMKL, bmk, nullptr, 1.f, X, nullptr, 128, 512);
  // 5. k16 = bf16((key @ Wk + bk) * modk)
  mgemm_kernel<128, 64, 4><<<dim3(8, 64), blk, 0, stream>>>(
      key_i, ws16 + W_WKH, ws16 + W_WKL, bk, X, 1.f, nullptr, k16, 512, 512);
  // 6. attention pass A: partial denominators (q16,k16 ready)
  attn_lsum_kernel<<<dim3(4096), blk, 0, stream>>>(q16, k16, lsum4);
  // 7. v16 = bf16(value @ Wv + bv)   (-> X, modk dead)
  mgemm_kernel<128, 64, 2><<<dim3(8, 64), blk, 0, stream>>>(
      value, ws16 + W_WVH, ws16 + W_WVL, bv, nullptr, 1.f, nullptr, v16, 512, 512);
  // 8. V^T per (b,h)
  vtrans_kernel<<<dim3(1024), blk, 0, stream>>>(v16, vt);
  // 9. attention pass B: AW -> out tail, ao -> X (v16 dead)
  attn_pv_kernel<<<dim3(1024), blk, 0, stream>>>(q16, k16, vt, lsum4, AW, ao);
  // 10. output = ao @ Wo + bo
  mgemm_kernel<128, 64, 0><<<dim3(8, 64), blk, 0, stream>>>(
      ao, ws16 + W_WOH, ws16 + W_WOL, bo, nullptr, 1.f, out, nullptr, 512, 512);
}